// Round 1
// 118.442 us; speedup vs baseline: 1.0673x; 1.0673x over previous
//
#include <hip/hip_runtime.h>
#include <math.h>

// Highpass biquad: FIR(b0,b1,b2) + IIR(a1,a2) recurrence, clamp [-1,1].
// R9: issue-density build. R8 post-mortem: kernel fell below the harness
// fills (<41us) but stays ~2x off its ~16-21us traffic floor. BANK_CONFLICT
// =0 and traffic is minimal, so the residual is per-wave ISSUE OVERHEAD:
// stride-65 (+1 pad) LDS breaks 16B alignment -> 324 scalar LDS ops/wave
// (68 ds_write_b32 stage, 128 scalar warmup/main, 64 scalar store reads),
// stretching wave lifetime and thinning vmem issue density to ~10.6 B/cyc
// vs the 10.25 B/cyc HBM floor (marginal).
// Fix: (1) XOR-swizzled LINEAR layout, f4 granularity:
//        slot(r,p') = 16r | (p' ^ (r&15)), stride 64, no pad.
//      Every phase is bank-quad balanced: bank quad of a b128 access is
//      (j4 ^ (r&15)) mod 8; across the wave each of the 8 quads serves
//      exactly 8 lanes x 16B = the 128 B/cyc LDS hardware optimum ->
//      conflict-free with full ds_read_b128/ds_write_b128.
//      (2) global_load_lds width=16 staging (linear LDS dest = 64k+tid
//      slots; per-lane INVERSE-swizzled global source, rule both-sides-
//      or-neither). No VGPR round trip, no ds_writes.
//      (3) 64 rows (no head row) = exactly 16 KB LDS -> 10 blocks/CU
//      (was 9 at 16.9 KB). Thread 0's warmup head (prev-segment tail)
//      is pre-fetched into registers by 16 exec-masked f4 loads and
//      blended via per-element select -> no divergent duplicate loop.
// Row r (0..63) = global chunk S/64 + r. Thread t: warmup over row t-1
// (t=0: register head), main in-place over row t, coalesced f4 store.
// In-wave program order makes in-place safe: all warmup reads of row t
// (by thread t+1) precede all main writes of row t (single wave,
// DS pipe is in-order per wave).
// Coefficients in float (HW v_sin/v_cos): err ~1e-7 << absmax 3.9e-3,
// threshold 1.06e-2. Warmup length 64: boundary err 0.904^64 ~ 1.6e-3.

constexpr int T_LEN  = 131072;
constexpr int L       = 64;              // samples per chunk (= per thread)
constexpr int CPB     = 64;              // chunks per block = 1 wave
constexpr int SEG     = CPB * L;         // 4096 floats per block segment
constexpr int BLK_PER_SEQ = T_LEN / SEG; // 32
constexpr int NSEQ    = 64 * 2;          // 128 sequences
constexpr int NBLOCKS = NSEQ * BLK_PER_SEQ; // 4096

typedef float fx4 __attribute__((ext_vector_type(4)));

#define AS1(p) ((const __attribute__((address_space(1))) void*)(p))
#define AS3(p) ((__attribute__((address_space(3))) void*)(p))

__global__ __launch_bounds__(64) void hp_kernel(
    const float* __restrict__ x,
    const float* __restrict__ pfreq,
    const float* __restrict__ pq,
    float* __restrict__ out)
{
    __shared__ fx4 lds4[CPB * 16];           // 64 rows x 16 f4 = 16384 B

    // --- coefficients (float; HW trig) ---
    float freq = fminf(fmaxf(pfreq[0], 100.0f), 44100.0f * 0.5f - 1.0f);
    float q    = fminf(fmaxf(pq[0], 0.1f), 10.0f);
    float w0   = 2.0f * (float)M_PI * freq / 44100.0f;
    float cw   = cosf(w0);
    float alpha = sinf(w0) / (2.0f * q);
    float ia0  = 1.0f / (1.0f + alpha);
    const float b0 = (1.0f + cw) * 0.5f * ia0;
    const float b1 = -(1.0f + cw) * ia0;
    const float b2 = b0;
    const float a1 = -2.0f * cw * ia0;
    const float a2 = (1.0f - alpha) * ia0;

    const int b   = blockIdx.x;
    const int seq = b >> 5;                  // / BLK_PER_SEQ
    const int S   = (b & (BLK_PER_SEQ - 1)) * SEG;
    const float* __restrict__ xs = x   + (size_t)seq * T_LEN;
    float*       __restrict__ os = out + (size_t)seq * T_LEN;
    const int tid = threadIdx.x;

    // --- stage: segment f4 g -> swizzled slot. global_load_lds writes
    // lane's 16B at (uniform base + lane*16) = slot 64k+tid; so lane
    // fetches the global f4 whose slot that is (inverse swizzle). ---
    {
        const float* gseg = xs + S;
#pragma unroll
        for (int k = 0; k < 16; ++k) {
            int s = tid + (k << 6);              // dest slot
            int r = s >> 4;
            int g = (r << 4) | ((s & 15) ^ (r & 15));  // source f4 index
            __builtin_amdgcn_global_load_lds(AS1(gseg + (g << 2)),
                                             AS3(lds4 + (k << 6)), 16, 0, 0);
        }
    }

    // thread 0's warmup head = prev segment tail, to registers (masked)
    fx4 h[16];
    if (tid == 0 && S > 0) {
        const fx4* gw = (const fx4*)(xs + S - L);
#pragma unroll
        for (int k = 0; k < 16; ++k) h[k] = gw[k];
    }

    __syncthreads();                         // vmcnt(0): LDS DMA done

    float y1 = 0.f, y2 = 0.f, p1 = 0.f, p2 = 0.f;

    // y = (xf - a2*y2) - a1*y1 => critical path y1->y is one FMA (~4cyc)
#define STEP(xv) { \
        float xf_ = fmaf(b2, p2, fmaf(b1, p1, b0 * (xv))); \
        float yv  = fmaf(-a1, y1, fmaf(-a2, y2, xf_)); \
        p2 = p1; p1 = (xv); y2 = y1; y1 = yv; }

    // --- warmup: thread t converges state over chunk cgm-1 ---
    const int cgm = (S >> 6) + tid;          // global index of main chunk
    if (cgm >= 1) {
        if (cgm >= 2) {                      // ICs = tail of chunk cgm-2
            if (tid >= 2) {
                int rr = tid - 2;            // row rr, samples 62,63
                const float* pr = (const float*)(lds4 + ((rr << 4) | (15 ^ (rr & 15))));
                p2 = pr[2]; p1 = pr[3];
            } else {                         // not staged: 2 global loads
                const float* w = xs + S + (tid - 1) * L;
                p1 = w[-1]; p2 = w[-2];
            }
        }                                    // cgm==1: zero ICs (exact)
        const fx4* rp = lds4 + (((tid - 1) & 63) << 4);
        const int  xr = (tid - 1) & 15;
#pragma unroll
        for (int j4 = 0; j4 < 16; ++j4) {
            fx4 v = (tid == 0) ? h[j4] : rp[j4 ^ xr];
            STEP(v.x); STEP(v.y); STEP(v.z); STEP(v.w);
        }
    }
    // cgm == 0: exact zero initial conditions (matches reference padding)

    // --- main: in-place over row tid. Safe without a barrier: one wave,
    // in-order DS pipe -> all warmup reads of row tid (thread tid+1)
    // retire before any main write (program order). ---
    {
        fx4* mrow = lds4 + (tid << 4);
        const int xm = tid & 15;
#pragma unroll
        for (int j4 = 0; j4 < 16; ++j4) {
            int idx = j4 ^ xm;
            fx4 v = mrow[idx];
            fx4 o;
            STEP(v.x); o.x = fminf(fmaxf(y1, -1.f), 1.f);
            STEP(v.y); o.y = fminf(fmaxf(y1, -1.f), 1.f);
            STEP(v.z); o.z = fminf(fmaxf(y1, -1.f), 1.f);
            STEP(v.w); o.w = fminf(fmaxf(y1, -1.f), 1.f);
            mrow[idx] = o;
        }
    }
    __syncthreads();                         // ~free (1 wave); drain lgkm

    // --- coalesced output: swizzled slots -> contiguous f4 stores ---
    {
        fx4* ob = (fx4*)(os + S);
#pragma unroll
        for (int k = 0; k < 16; ++k) {
            int f = tid + (k << 6);          // output f4 index
            int r = f >> 4;
            ob[f] = lds4[(r << 4) | ((f & 15) ^ (r & 15))];
        }
    }
#undef STEP
}

extern "C" void kernel_launch(void* const* d_in, const int* in_sizes, int n_in,
                              void* d_out, int out_size, void* d_ws, size_t ws_size,
                              hipStream_t stream) {
    const float* x  = (const float*)d_in[0];
    // d_in[1] = t, unused by the reference computation
    const float* ff = (const float*)d_in[2];
    const float* fq = (const float*)d_in[3];
    float* out = (float*)d_out;
    hp_kernel<<<NBLOCKS, CPB, 0, stream>>>(x, ff, fq, out);
}